// Round 14
// baseline (83.228 us; speedup 1.0000x reference)
//
#include <hip/hip_runtime.h>

#define BH  64
#define SEQ 4096
#define DH  64
#define NCHUNK 32
#define CROWS  (SEQ / NCHUNK)   // 128 rows per chunk; wave w owns rows w*32..w*32+32

typedef __attribute__((ext_vector_type(8))) short bf16x8v;  // 8 bf16 (4 VGPR)
typedef __attribute__((ext_vector_type(4))) float f32x4v;   // MFMA acc

// fp32 -> bf16, round-to-nearest-even
__device__ __forceinline__ short f2bf(float x) {
  unsigned u = __float_as_uint(x);
  return (short)((u + 0x7FFFu + ((u >> 16) & 1u)) >> 16);
}

// ---------------------------------------------------------------------------
// Kernel 1: partial kv = k^T v over a 128-row chunk. One (b,h,chunk)/block,
// 256 threads = 4 waves; wave w owns K-step rows [w*32, w*32+32) and the
// FULL 64x64 output in registers (4x4 MFMA 16x16 tiles).
// STRAIGHT-LINE body (no K-loop): all 64 fragment dwords batch-issued to
// registers (compiler cannot roll it -> 64 outstanding loads per wave),
// then cvt->bf16, then 16 MFMA. No LDS staging, no main-loop barriers,
// no vmcnt chains: pure TLP (8 waves/CU x 16 KB in flight) drives HBM/L3.
// One end-of-kernel LDS tree-reduce (round-8-proven) combines the 4 waves.
// Fragment & C/D layouts HW-verified rounds 10-13 (absmax 16 vs thr 61.8).
// ---------------------------------------------------------------------------
__global__ __launch_bounds__(256) void kv_partial_kernel(
    const float* __restrict__ k, const float* __restrict__ v,
    float* __restrict__ partial) {
  const int t = threadIdx.x;
  const int bh = blockIdx.x >> 5;             // / NCHUNK
  const int chunk = blockIdx.x & (NCHUNK - 1);
  const int l  = t & 63;
  const int w  = t >> 6;
  const int lg = l >> 4;     // 0..3
  const int ln = l & 15;     // 0..15

  const size_t rowbase = (size_t)bh * SEQ * DH + ((size_t)chunk * CROWS + w * 32) * DH;
  const float* kb = k + rowbase;
  const float* vb = v + rowbase;

  __shared__ float smem[8192];   // 32 KB, used ONLY for the final reduce

  // ---- batch-load all fragments: 64 independent dwords per lane ----
  float kf[32], vf[32];
#pragma unroll
  for (int j = 0; j < 8; ++j) {
    const float* kr = kb + (size_t)(lg * 8 + j) * DH;
    const float* vr = vb + (size_t)(lg * 8 + j) * DH;
#pragma unroll
    for (int m = 0; m < 4; ++m) {
      kf[m * 8 + j] = kr[m * 16 + ln];
      vf[m * 8 + j] = vr[m * 16 + ln];
    }
  }

  // ---- convert to bf16 fragments ----
  bf16x8v a[4], b[4];
#pragma unroll
  for (int m = 0; m < 4; ++m)
#pragma unroll
    for (int j = 0; j < 8; ++j) {
      a[m][j] = f2bf(kf[m * 8 + j]);
      b[m][j] = f2bf(vf[m * 8 + j]);
    }

  // ---- 16 MFMA: full 64x64 for this 32-row K-step ----
  f32x4v acc[4][4];
#pragma unroll
  for (int m = 0; m < 4; ++m)
#pragma unroll
    for (int n = 0; n < 4; ++n) {
      acc[m][n] = (f32x4v){0.f, 0.f, 0.f, 0.f};
      acc[m][n] = __builtin_amdgcn_mfma_f32_16x16x32_bf16(
          a[m], b[n], acc[m][n], 0, 0, 0);
    }

  // ---- cross-wave tree reduce through LDS (round-8-proven pattern) ----
  // wave region layout: float4 slot (m*4+n) at [slot*256 + l*4]
  if (w >= 2) {
    float* reg = smem + (w - 2) * 4096;
#pragma unroll
    for (int m = 0; m < 4; ++m)
#pragma unroll
      for (int n = 0; n < 4; ++n) {
        float4 x = {acc[m][n][0], acc[m][n][1], acc[m][n][2], acc[m][n][3]};
        *(float4*)&reg[(m * 4 + n) * 256 + l * 4] = x;
      }
  }
  __syncthreads();
  if (w < 2) {
    const float* reg = smem + w * 4096;
#pragma unroll
    for (int m = 0; m < 4; ++m)
#pragma unroll
      for (int n = 0; n < 4; ++n) {
        float4 x = *(const float4*)&reg[(m * 4 + n) * 256 + l * 4];
        acc[m][n][0] += x.x; acc[m][n][1] += x.y;
        acc[m][n][2] += x.z; acc[m][n][3] += x.w;
      }
  }
  __syncthreads();
  if (w == 1) {
#pragma unroll
    for (int m = 0; m < 4; ++m)
#pragma unroll
      for (int n = 0; n < 4; ++n) {
        float4 x = {acc[m][n][0], acc[m][n][1], acc[m][n][2], acc[m][n][3]};
        *(float4*)&smem[(m * 4 + n) * 256 + l * 4] = x;
      }
  }
  __syncthreads();
  if (w == 0) {
    float* pb = partial + (size_t)blockIdx.x * (DH * DH);
#pragma unroll
    for (int m = 0; m < 4; ++m)
#pragma unroll
      for (int n = 0; n < 4; ++n) {
        float4 x = *(const float4*)&smem[(m * 4 + n) * 256 + l * 4];
        acc[m][n][0] += x.x; acc[m][n][1] += x.y;
        acc[m][n][2] += x.z; acc[m][n][3] += x.w;
        // C/D layout (HW-verified): col = ln, row = lg*4 + r
#pragma unroll
        for (int r = 0; r < 4; ++r)
          pb[(m * 16 + lg * 4 + r) * 64 + n * 16 + ln] = acc[m][n][r];
      }
  }
}

// ---------------------------------------------------------------------------
// Kernel 2: reduce partials -> kvf [BH][64*64]. 256 blocks x 256 threads
// covers 65536 float4 slots.
// ---------------------------------------------------------------------------
__global__ __launch_bounds__(256) void kv_reduce_kernel(
    const float* __restrict__ partial, float* __restrict__ kvf) {
  const int gid = blockIdx.x * 256 + threadIdx.x;
  const int bh = gid >> 10;
  const int idx = gid & 1023;
  float4 s = {0.f, 0.f, 0.f, 0.f};
  for (int c = 0; c < NCHUNK; ++c) {
    const float4* p = (const float4*)(partial + ((size_t)bh * NCHUNK + c) * (DH * DH));
    float4 x = p[idx];
    s.x += x.x; s.y += x.y; s.z += x.z; s.w += x.w;
  }
  ((float4*)kvf)[gid] = s;
}

// ---------------------------------------------------------------------------
// Kernel 3: out = q @ kv. Block = 64 q-rows. Thread = 1 row x 16 cols.
// Entire q row hoisted to registers up front; kv in LDS, broadcast reads.
// Near its BW roofline (~19 us vs 20 ideal) -- unchanged.
// ---------------------------------------------------------------------------
__global__ __launch_bounds__(256) void out_kernel(
    const float* __restrict__ q, const float* __restrict__ kvf,
    float* __restrict__ out) {
  const int t = threadIdx.x;
  const int bh = blockIdx.x >> 6;
  const int rb = blockIdx.x & 63;
  const int row = rb * 64 + (t >> 2);
  const int c0 = (t & 3) * 16;

  __shared__ float kv_lds[64 * 64];

  const float4* gkv4 = (const float4*)(kvf + (size_t)bh * (DH * DH));
  float4* kv4 = (float4*)kv_lds;
#pragma unroll
  for (int j = 0; j < 4; ++j) kv4[t + j * 256] = gkv4[t + j * 256];

  const float* qrow = q + (size_t)bh * SEQ * DH + (size_t)row * DH;
  float4 qv[16];
#pragma unroll
  for (int i = 0; i < 16; ++i) qv[i] = *(const float4*)&qrow[i * 4];

  __syncthreads();

  float acc[16];
#pragma unroll
  for (int j = 0; j < 16; ++j) acc[j] = 0.f;

#pragma unroll
  for (int dc = 0; dc < 16; ++dc) {
    float qs[4] = {qv[dc].x, qv[dc].y, qv[dc].z, qv[dc].w};
#pragma unroll
    for (int dd = 0; dd < 4; ++dd) {
      const float* kr = &kv_lds[(dc * 4 + dd) * 64 + c0];
      float4 k0 = *(const float4*)&kr[0];
      float4 k1 = *(const float4*)&kr[4];
      float4 k2 = *(const float4*)&kr[8];
      float4 k3 = *(const float4*)&kr[12];
      const float qsv = qs[dd];
      acc[0]  += qsv * k0.x; acc[1]  += qsv * k0.y;
      acc[2]  += qsv * k0.z; acc[3]  += qsv * k0.w;
      acc[4]  += qsv * k1.x; acc[5]  += qsv * k1.y;
      acc[6]  += qsv * k1.z; acc[7]  += qsv * k1.w;
      acc[8]  += qsv * k2.x; acc[9]  += qsv * k2.y;
      acc[10] += qsv * k2.z; acc[11] += qsv * k2.w;
      acc[12] += qsv * k3.x; acc[13] += qsv * k3.y;
      acc[14] += qsv * k3.z; acc[15] += qsv * k3.w;
    }
  }

  float* ob = out + (size_t)bh * SEQ * DH + (size_t)row * DH + c0;
#pragma unroll
  for (int j = 0; j < 4; ++j) {
    float4 w = {acc[4 * j + 0], acc[4 * j + 1], acc[4 * j + 2], acc[4 * j + 3]};
    *(float4*)&ob[4 * j] = w;
  }
}

// ---------------------------------------------------------------------------
extern "C" void kernel_launch(void* const* d_in, const int* in_sizes, int n_in,
                              void* d_out, int out_size, void* d_ws, size_t ws_size,
                              hipStream_t stream) {
  const float* q = (const float*)d_in[0];
  const float* k = (const float*)d_in[1];
  const float* v = (const float*)d_in[2];
  float* out = (float*)d_out;

  float* kvf = (float*)d_ws;                      // [BH][64*64] = 1 MB
  float* partial = kvf + (size_t)BH * DH * DH;    // [BH*NCHUNK][64*64] = 32 MB

  hipLaunchKernelGGL(kv_partial_kernel, dim3(BH * NCHUNK), dim3(256), 0, stream,
                     k, v, partial);
  hipLaunchKernelGGL(kv_reduce_kernel, dim3(256), dim3(256), 0, stream,
                     partial, kvf);
  hipLaunchKernelGGL(out_kernel, dim3(BH * 64), dim3(256), 0, stream,
                     q, kvf, out);
}

// Round 15
// 76.746 us; speedup vs baseline: 1.0845x; 1.0845x over previous
//
#include <hip/hip_runtime.h>

#define BH  64
#define SEQ 4096
#define DH  64
#define NCHUNK 8
#define CROWS  (SEQ / NCHUNK)   // 512 rows per chunk; wave w owns 128 rows = 4 K-steps

typedef __attribute__((ext_vector_type(8))) short bf16x8v;  // 8 bf16 (4 VGPR)
typedef __attribute__((ext_vector_type(4))) float f32x4v;   // MFMA acc

// fp32 -> bf16, round-to-nearest-even
__device__ __forceinline__ short f2bf(float x) {
  unsigned u = __float_as_uint(x);
  return (short)((u + 0x7FFFu + ((u >> 16) & 1u)) >> 16);
}

// ---------------------------------------------------------------------------
// Kernel 1: partial kv = k^T v over a 512-row chunk. One (b,h,chunk)/block,
// 256 threads = 4 waves; wave w owns rows [w*128, w*128+128) = 4 K-steps of
// 32 rows, accumulating the FULL 64x64 output in registers.
// __launch_bounds__(256, 2): 256-VGPR budget so the 64-dword load batches
// (ping/pong register buffers, ~210 VGPR live) are NOT serialized by the
// allocator (round-14 failure: default budget -> VGPR 76 -> rolled loads).
// Fully unrolled 4-step pipeline: L0 L1 C0 L2 C1 L3 C2 C3 -- each wave keeps
// ~63 loads (16 KB) outstanding continuously; zero barriers, zero LDS in the
// hot path. One end-of-kernel LDS tree-reduce combines the 4 waves.
// Fragment & C/D layouts HW-verified rounds 10-14 (absmax 16 vs thr 61.8).
// ---------------------------------------------------------------------------
#define LOADSTEP(kf, vf, step)                                              \
  do {                                                                      \
    const float* kp_ = kb + (size_t)(step) * 32 * DH;                       \
    const float* vp_ = vb + (size_t)(step) * 32 * DH;                       \
    _Pragma("unroll")                                                       \
    for (int j = 0; j < 8; ++j) {                                           \
      _Pragma("unroll")                                                     \
      for (int m = 0; m < 4; ++m) {                                         \
        kf[m * 8 + j] = kp_[(size_t)(lg * 8 + j) * DH + m * 16 + ln];       \
        vf[m * 8 + j] = vp_[(size_t)(lg * 8 + j) * DH + m * 16 + ln];       \
      }                                                                     \
    }                                                                       \
  } while (0)

#define COMPUTESTEP(kf, vf)                                                 \
  do {                                                                      \
    bf16x8v a_[4], b_[4];                                                   \
    _Pragma("unroll")                                                       \
    for (int m = 0; m < 4; ++m) {                                           \
      _Pragma("unroll")                                                     \
      for (int j = 0; j < 8; ++j) {                                         \
        a_[m][j] = f2bf(kf[m * 8 + j]);                                     \
        b_[m][j] = f2bf(vf[m * 8 + j]);                                     \
      }                                                                     \
    }                                                                       \
    _Pragma("unroll")                                                       \
    for (int m = 0; m < 4; ++m) {                                           \
      _Pragma("unroll")                                                     \
      for (int n = 0; n < 4; ++n)                                           \
        acc[m][n] = __builtin_amdgcn_mfma_f32_16x16x32_bf16(                \
            a_[m], b_[n], acc[m][n], 0, 0, 0);                              \
    }                                                                       \
  } while (0)

__global__ __launch_bounds__(256, 2) void kv_partial_kernel(
    const float* __restrict__ k, const float* __restrict__ v,
    float* __restrict__ partial) {
  const int t = threadIdx.x;
  const int bh = blockIdx.x >> 3;             // / NCHUNK
  const int chunk = blockIdx.x & (NCHUNK - 1);
  const int l  = t & 63;
  const int w  = t >> 6;
  const int lg = l >> 4;     // 0..3
  const int ln = l & 15;     // 0..15

  const size_t rowbase =
      (size_t)bh * SEQ * DH + ((size_t)chunk * CROWS + w * 128) * DH;
  const float* kb = k + rowbase;
  const float* vb = v + rowbase;

  __shared__ float smem[8192];   // 32 KB, used ONLY for the final reduce

  f32x4v acc[4][4];
#pragma unroll
  for (int m = 0; m < 4; ++m)
#pragma unroll
    for (int n = 0; n < 4; ++n) acc[m][n] = (f32x4v){0.f, 0.f, 0.f, 0.f};

  float kA[32], vA[32], kB[32], vB[32];

  LOADSTEP(kA, vA, 0);
  LOADSTEP(kB, vB, 1);
  __builtin_amdgcn_sched_barrier(0);
  COMPUTESTEP(kA, vA);
  __builtin_amdgcn_sched_barrier(0);
  LOADSTEP(kA, vA, 2);
  __builtin_amdgcn_sched_barrier(0);
  COMPUTESTEP(kB, vB);
  __builtin_amdgcn_sched_barrier(0);
  LOADSTEP(kB, vB, 3);
  __builtin_amdgcn_sched_barrier(0);
  COMPUTESTEP(kA, vA);
  __builtin_amdgcn_sched_barrier(0);
  COMPUTESTEP(kB, vB);

  // ---- cross-wave tree reduce through LDS (round-8/14-proven pattern) ----
  if (w >= 2) {
    float* reg = smem + (w - 2) * 4096;
#pragma unroll
    for (int m = 0; m < 4; ++m)
#pragma unroll
      for (int n = 0; n < 4; ++n) {
        float4 x = {acc[m][n][0], acc[m][n][1], acc[m][n][2], acc[m][n][3]};
        *(float4*)&reg[(m * 4 + n) * 256 + l * 4] = x;
      }
  }
  __syncthreads();
  if (w < 2) {
    const float* reg = smem + w * 4096;
#pragma unroll
    for (int m = 0; m < 4; ++m)
#pragma unroll
      for (int n = 0; n < 4; ++n) {
        float4 x = *(const float4*)&reg[(m * 4 + n) * 256 + l * 4];
        acc[m][n][0] += x.x; acc[m][n][1] += x.y;
        acc[m][n][2] += x.z; acc[m][n][3] += x.w;
      }
  }
  __syncthreads();
  if (w == 1) {
#pragma unroll
    for (int m = 0; m < 4; ++m)
#pragma unroll
      for (int n = 0; n < 4; ++n) {
        float4 x = {acc[m][n][0], acc[m][n][1], acc[m][n][2], acc[m][n][3]};
        *(float4*)&smem[(m * 4 + n) * 256 + l * 4] = x;
      }
  }
  __syncthreads();
  if (w == 0) {
    float* pb = partial + (size_t)blockIdx.x * (DH * DH);
#pragma unroll
    for (int m = 0; m < 4; ++m)
#pragma unroll
      for (int n = 0; n < 4; ++n) {
        float4 x = *(const float4*)&smem[(m * 4 + n) * 256 + l * 4];
        acc[m][n][0] += x.x; acc[m][n][1] += x.y;
        acc[m][n][2] += x.z; acc[m][n][3] += x.w;
        // C/D layout (HW-verified): col = ln, row = lg*4 + r
#pragma unroll
        for (int r = 0; r < 4; ++r)
          pb[(m * 16 + lg * 4 + r) * 64 + n * 16 + ln] = acc[m][n][r];
      }
  }
}

// ---------------------------------------------------------------------------
// Kernel 2: reduce partials -> kvf [BH][64*64]. 256 blocks x 256 threads
// covers 65536 float4 slots.
// ---------------------------------------------------------------------------
__global__ __launch_bounds__(256) void kv_reduce_kernel(
    const float* __restrict__ partial, float* __restrict__ kvf) {
  const int gid = blockIdx.x * 256 + threadIdx.x;
  const int bh = gid >> 10;
  const int idx = gid & 1023;
  float4 s = {0.f, 0.f, 0.f, 0.f};
  for (int c = 0; c < NCHUNK; ++c) {
    const float4* p = (const float4*)(partial + ((size_t)bh * NCHUNK + c) * (DH * DH));
    float4 x = p[idx];
    s.x += x.x; s.y += x.y; s.z += x.z; s.w += x.w;
  }
  ((float4*)kvf)[gid] = s;
}

// ---------------------------------------------------------------------------
// Kernel 3: out = q @ kv. Block = 64 q-rows. Thread = 1 row x 16 cols.
// Entire q row hoisted to registers up front; kv in LDS, broadcast reads.
// Near its BW roofline (~19 us, 6.7 TB/s effective) -- unchanged.
// ---------------------------------------------------------------------------
__global__ __launch_bounds__(256) void out_kernel(
    const float* __restrict__ q, const float* __restrict__ kvf,
    float* __restrict__ out) {
  const int t = threadIdx.x;
  const int bh = blockIdx.x >> 6;
  const int rb = blockIdx.x & 63;
  const int row = rb * 64 + (t >> 2);
  const int c0 = (t & 3) * 16;

  __shared__ float kv_lds[64 * 64];

  const float4* gkv4 = (const float4*)(kvf + (size_t)bh * (DH * DH));
  float4* kv4 = (float4*)kv_lds;
#pragma unroll
  for (int j = 0; j < 4; ++j) kv4[t + j * 256] = gkv4[t + j * 256];

  const float* qrow = q + (size_t)bh * SEQ * DH + (size_t)row * DH;
  float4 qv[16];
#pragma unroll
  for (int i = 0; i < 16; ++i) qv[i] = *(const float4*)&qrow[i * 4];

  __syncthreads();

  float acc[16];
#pragma unroll
  for (int j = 0; j < 16; ++j) acc[j] = 0.f;

#pragma unroll
  for (int dc = 0; dc < 16; ++dc) {
    float qs[4] = {qv[dc].x, qv[dc].y, qv[dc].z, qv[dc].w};
#pragma unroll
    for (int dd = 0; dd < 4; ++dd) {
      const float* kr = &kv_lds[(dc * 4 + dd) * 64 + c0];
      float4 k0 = *(const float4*)&kr[0];
      float4 k1 = *(const float4*)&kr[4];
      float4 k2 = *(const float4*)&kr[8];
      float4 k3 = *(const float4*)&kr[12];
      const float qsv = qs[dd];
      acc[0]  += qsv * k0.x; acc[1]  += qsv * k0.y;
      acc[2]  += qsv * k0.z; acc[3]  += qsv * k0.w;
      acc[4]  += qsv * k1.x; acc[5]  += qsv * k1.y;
      acc[6]  += qsv * k1.z; acc[7]  += qsv * k1.w;
      acc[8]  += qsv * k2.x; acc[9]  += qsv * k2.y;
      acc[10] += qsv * k2.z; acc[11] += qsv * k2.w;
      acc[12] += qsv * k3.x; acc[13] += qsv * k3.y;
      acc[14] += qsv * k3.z; acc[15] += qsv * k3.w;
    }
  }

  float* ob = out + (size_t)bh * SEQ * DH + (size_t)row * DH + c0;
#pragma unroll
  for (int j = 0; j < 4; ++j) {
    float4 w = {acc[4 * j + 0], acc[4 * j + 1], acc[4 * j + 2], acc[4 * j + 3]};
    *(float4*)&ob[4 * j] = w;
  }
}

// ---------------------------------------------------------------------------
extern "C" void kernel_launch(void* const* d_in, const int* in_sizes, int n_in,
                              void* d_out, int out_size, void* d_ws, size_t ws_size,
                              hipStream_t stream) {
  const float* q = (const float*)d_in[0];
  const float* k = (const float*)d_in[1];
  const float* v = (const float*)d_in[2];
  float* out = (float*)d_out;

  float* kvf = (float*)d_ws;                      // [BH][64*64] = 1 MB
  float* partial = kvf + (size_t)BH * DH * DH;    // [BH*NCHUNK][64*64] = 8 MB

  hipLaunchKernelGGL(kv_partial_kernel, dim3(BH * NCHUNK), dim3(256), 0, stream,
                     k, v, partial);
  hipLaunchKernelGGL(kv_reduce_kernel, dim3(256), dim3(256), 0, stream,
                     partial, kvf);
  hipLaunchKernelGGL(out_kernel, dim3(BH * 64), dim3(256), 0, stream,
                     q, kvf, out);
}